// Round 13
// baseline (218.180 us; speedup 1.0000x reference)
//
#include <hip/hip_runtime.h>
#include <stdint.h>
#include <stddef.h>

typedef __bf16 bf16;
typedef __bf16 bf16x8 __attribute__((ext_vector_type(8)));
typedef __bf16 bf16x4 __attribute__((ext_vector_type(4)));
typedef short short4v __attribute__((ext_vector_type(4)));
typedef float f32x4 __attribute__((ext_vector_type(4)));

#define GAS __attribute__((address_space(1)))
#define LAS __attribute__((address_space(3)))

__device__ __forceinline__ void async_load16(const void* g, void* l) {
  __builtin_amdgcn_global_load_lds((const GAS void*)g, (LAS void*)l, 16, 0, 0);
}

// 16x16x16 bf16 MFMA. C-layout of a 16x16 MFMA == B-layout of this shape,
// so P^T feeds PV straight from registers. Host pass gets a stub.
__device__ __forceinline__ f32x4 mfma16(bf16x4 a, bf16x4 b, f32x4 c) {
#if defined(__HIP_DEVICE_COMPILE__)
#if __has_builtin(__builtin_amdgcn_mfma_f32_16x16x16bf16_1k)
  return __builtin_amdgcn_mfma_f32_16x16x16bf16_1k(
      __builtin_bit_cast(short4v, a), __builtin_bit_cast(short4v, b), c, 0, 0, 0);
#else
  f32x4 d;
  asm volatile("v_mfma_f32_16x16x16_bf16 %0, %1, %2, %3"
               : "=v"(d)
               : "v"(a), "v"(b), "v"(c));
  return d;
#endif
#else
  (void)a; (void)b;
  return c;
#endif
}

// ---------------------------------------------------------------------------
// Kernel 1: fp32 -> bf16 casts, x4 vectorized. Wq pre-scaled by 0.125*log2(e)
// so QK^T lands in the exp2 domain (scores bounded -> no max subtraction).
// ---------------------------------------------------------------------------
__global__ __launch_bounds__(256) void cast_all(
    const float* __restrict__ x, const float* __restrict__ Wq,
    const float* __restrict__ Wk, const float* __restrict__ Wv,
    const float* __restrict__ Wo, bf16* __restrict__ Xh,
    bf16* __restrict__ Wqkv, bf16* __restrict__ Woh) {
  int idx = (blockIdx.x * 256 + threadIdx.x) * 4;
  const float* src;
  bf16* dst;
  float scale = 1.0f;
  if (idx < 4194304) {
    src = x + idx; dst = Xh + idx;
  } else if (idx < 7340032) {
    int j = idx - 4194304;
    if (j < 1048576) {
      src = Wq + j; scale = 0.18033688011112042f;
    } else {
      src = ((j < 2097152) ? Wk : Wv) + (j & 1048575);
    }
    dst = Wqkv + j;
  } else {
    int j = idx - 7340032;
    src = Wo + j; dst = Woh + j;
  }
  float4 v = *(const float4*)src;
  bf16x4 o;
  o[0] = (bf16)(v.x * scale); o[1] = (bf16)(v.y * scale);
  o[2] = (bf16)(v.z * scale); o[3] = (bf16)(v.w * scale);
  *(bf16x4*)dst = o;
}

// ---------------------------------------------------------------------------
// Kernel 2: QKV projection with FUSED RoPE + V-transpose epilogue.
// C-layout puts rope pairs (col 2k, 2k+1) in adjacent lanes -> shfl_xor(1)
// exchange + in-register rotation on fp32 acc. Q -> Qh, K -> Kh (both
// [bh][s][64]), V -> Vt[bh][64][2048]. QKV intermediate buffer eliminated.
// ---------------------------------------------------------------------------
__global__ __launch_bounds__(256) void gemm_qkv(
    const bf16* __restrict__ A, const bf16* __restrict__ B,
    bf16* __restrict__ Qh, bf16* __restrict__ Kh, bf16* __restrict__ Vt,
    int K) {
  __shared__ __align__(16) bf16 As[128 * 32];
  __shared__ __align__(16) bf16 Bs[128 * 32];
  const int tid = threadIdx.x;
  const int wave = tid >> 6, lane = tid & 63;
  const int bm = blockIdx.y * 128, bn = blockIdx.x * 128;
  const int wm = (wave >> 1) * 64, wn = (wave & 1) * 64;
  const int lrow = lane >> 2, lk = (lane & 3) * 8;
  const int fr = lane & 15, fk = (lane >> 4) * 8;

  f32x4 acc[4][4] = {};

  for (int kt = 0; kt < K; kt += 32) {
    __syncthreads();
#pragma unroll
    for (int c = 0; c < 2; ++c) {
      const int chunk = wave * 2 + c;
      const bf16* ga = A + (size_t)(bm + chunk * 16 + lrow) * K + kt + lk;
      async_load16(ga, (void*)(As + chunk * 512));
      const bf16* gb = B + (size_t)(bn + chunk * 16 + lrow) * K + kt + lk;
      async_load16(gb, (void*)(Bs + chunk * 512));
    }
    __syncthreads();

    bf16x8 af[4], bfr[4];
#pragma unroll
    for (int i = 0; i < 4; ++i)
      af[i] = *(const bf16x8*)&As[(wm + i * 16 + fr) * 32 + fk];
#pragma unroll
    for (int j = 0; j < 4; ++j)
      bfr[j] = *(const bf16x8*)&Bs[(wn + j * 16 + fr) * 32 + fk];
#pragma unroll
    for (int i = 0; i < 4; ++i)
#pragma unroll
      for (int j = 0; j < 4; ++j)
        acc[i][j] =
            __builtin_amdgcn_mfma_f32_16x16x32_bf16(af[i], bfr[j], acc[i][j], 0, 0, 0);
  }

  const int r0 = (lane >> 4) * 4, cc = lane & 15;
  const bool oddl = cc & 1;
#pragma unroll
  for (int i = 0; i < 4; ++i) {
    const int row0 = bm + wm + i * 16 + r0;
    const int b = row0 >> 11, s0 = row0 & 2047;
#pragma unroll
    for (int j = 0; j < 4; ++j) {
      const int col = bn + wn + j * 16 + cc;  // whole wave same region per j
      if (col < 2048) {
        // RoPE: pair partner is lane^1 (col 2k <-> 2k+1)
        const int hcol = col & 1023;
        const int h = hcol >> 6, d = hcol & 63;
        const int ip = d >> 1;
        const float freq = __expf((float)ip * -0.2878231366242557f);
        bf16* dst = (col < 1024 ? Qh : Kh) + ((size_t)(b * 16 + h) * 2048) * 64 + d;
#pragma unroll
        for (int r = 0; r < 4; ++r) {
          float own = acc[i][j][r];
          float oth = __shfl_xor(own, 1, 64);
          float sn, cs;
          __sincosf((float)(s0 + r) * freq, &sn, &cs);
          float res = oddl ? (oth * sn + own * cs) : (own * cs - oth * sn);
          dst[(size_t)(s0 + r) * 64] = (bf16)res;
        }
      } else {
        const int v = col - 2048, h = v >> 6, d = v & 63;
        bf16x4 o;
#pragma unroll
        for (int r = 0; r < 4; ++r) o[r] = (bf16)acc[i][j][r];
        *(bf16x4*)&Vt[(((size_t)b * 16 + h) * 64 + d) * 2048 + s0] = o;
      }
    }
  }
}

// ---------------------------------------------------------------------------
// Kernel 2b (out-proj): C(MxN) = A(MxK) @ B(NxK)^T, fp32 out.
// ---------------------------------------------------------------------------
template <typename OutT, int BM, int BN>
__global__ __launch_bounds__(256) void gemm_bt(
    const bf16* __restrict__ A, const bf16* __restrict__ B,
    OutT* __restrict__ C, int M, int N, int K) {
  constexpr int ACH = BM / 16, NCH = (BM + BN) / 16, PW = NCH / 4;
  constexpr int FM = BM / 32, FN = BN / 32;
  __shared__ __align__(16) bf16 As[BM * 32];
  __shared__ __align__(16) bf16 Bs[BN * 32];
  const int tid = threadIdx.x;
  const int wave = tid >> 6, lane = tid & 63;
  const int bm = blockIdx.y * BM, bn = blockIdx.x * BN;
  const int wm = (wave >> 1) * (BM / 2), wn = (wave & 1) * (BN / 2);
  const int lrow = lane >> 2, lk = (lane & 3) * 8;
  const int fr = lane & 15, fk = (lane >> 4) * 8;

  f32x4 acc[FM][FN] = {};

  for (int kt = 0; kt < K; kt += 32) {
    __syncthreads();
#pragma unroll
    for (int c = 0; c < PW; ++c) {
      const int chunk = wave * PW + c;
      if (chunk < ACH) {
        const bf16* ga = A + (size_t)(bm + chunk * 16 + lrow) * K + kt + lk;
        async_load16(ga, (void*)(As + chunk * 512));
      } else {
        const int bc = chunk - ACH;
        const bf16* gb = B + (size_t)(bn + bc * 16 + lrow) * K + kt + lk;
        async_load16(gb, (void*)(Bs + bc * 512));
      }
    }
    __syncthreads();

    bf16x8 af[FM], bfr[FN];
#pragma unroll
    for (int i = 0; i < FM; ++i)
      af[i] = *(const bf16x8*)&As[(wm + i * 16 + fr) * 32 + fk];
#pragma unroll
    for (int j = 0; j < FN; ++j)
      bfr[j] = *(const bf16x8*)&Bs[(wn + j * 16 + fr) * 32 + fk];
#pragma unroll
    for (int i = 0; i < FM; ++i)
#pragma unroll
      for (int j = 0; j < FN; ++j)
        acc[i][j] =
            __builtin_amdgcn_mfma_f32_16x16x32_bf16(af[i], bfr[j], acc[i][j], 0, 0, 0);
  }

  const int r0 = (lane >> 4) * 4, cc = lane & 15;
#pragma unroll
  for (int i = 0; i < FM; ++i)
#pragma unroll
    for (int j = 0; j < FN; ++j)
#pragma unroll
      for (int r = 0; r < 4; ++r)
        C[(size_t)(bm + wm + i * 16 + r0 + r) * N + (bn + wn + j * 16 + cc)] =
            (OutT)acc[i][j][r];
}

// ---------------------------------------------------------------------------
// Kernel 3: causal attention — round-12 structure + persistent pk prefetch.
// (128,2) caps 512/2 = 256 VGPRs; live state ~160+64acc fits (round 10's
// spill was the 4-wave/128-cap variant). Next tile's K/V loads issue right
// after QK consumes pk, overlapping the exp2+PV phase (~900 cyc) -> the
// per-tile L2/HBM stall leaves the serial chain.
// ---------------------------------------------------------------------------
__global__ __launch_bounds__(128, 2) void attn(const bf16* __restrict__ Qh,
                                               const bf16* __restrict__ Kh,
                                               const bf16* __restrict__ Vt,
                                               bf16* __restrict__ Oh) {
  __shared__ __align__(16) bf16 Vs[2][64 * 72];  // per-wave private
  __shared__ float scratch[68 * 64];             // combine area
  const int f = blockIdx.x;
  const int qt = 31 - (f >> 5);  // LPT: longest (qt=31) blocks dispatch first
  const int bh = f & 31;
  const int tid = threadIdx.x, w = tid >> 6, lane = tid & 63;
  const int nlo = lane & 15, g = lane >> 4;
  const int q0 = qt * 64;
  const bf16* __restrict__ Qp = Qh + (size_t)bh * 131072;
  const bf16* __restrict__ Kp = Kh + (size_t)bh * 131072;
  const bf16* __restrict__ Vp = Vt + (size_t)bh * 131072;
  const int n = qt + 1;          // total k-tiles for this Q-tile
  const int hf = (n + 1) >> 1;   // wave0: [0,hf), wave1: [hf,n)
  const int t0 = w ? hf : 0;
  const int cnt = w ? (n - hf) : hf;

  // Q fragments, all 4 q-subtiles (B-operand: n=q=nlo, k=d=g*8+j)
  bf16x8 aq[4][2];
#pragma unroll
  for (int qb = 0; qb < 4; ++qb)
#pragma unroll
    for (int ks = 0; ks < 2; ++ks)
      aq[qb][ks] =
          *(const bf16x8*)&Qp[(size_t)(q0 + qb * 16 + nlo) * 64 + ks * 32 + g * 8];

  f32x4 oacc[4][4] = {};  // [qb][d-block], O^T C-layout (m=d, n=q)
  float lsum[4] = {0.f, 0.f, 0.f, 0.f};

  // V staging geometry: instr c covers rows c*8..c*8+7
  const int srow = lane >> 3, soff = (lane & 7) * 8;
  bf16* __restrict__ Vw = Vs[w];

  // preamble: prefetch tile t0's K and V into persistent registers
  bf16x8 pv[8], pk[4][2];
  if (cnt > 0) {
#pragma unroll
    for (int c = 0; c < 8; ++c)
      pv[c] = *(const bf16x8*)&Vp[(size_t)(c * 8 + srow) * 2048 + t0 * 64 + soff];
#pragma unroll
    for (int ni = 0; ni < 4; ++ni)
#pragma unroll
      for (int ks = 0; ks < 2; ++ks)
        pk[ni][ks] = *(const bf16x8*)&Kp[(size_t)(t0 * 64 + ni * 16 + nlo) * 64 +
                                         ks * 32 + g * 8];
  }

  for (int it = 0; it < cnt; ++it) {
    const int i = t0 + it, kbase = i * 64;
    // commit V tile (wave-private; waitcnt ordering only, no barrier)
#pragma unroll
    for (int c = 0; c < 8; ++c)
      *(bf16x8*)&Vw[(c * 8 + srow) * 72 + soff] = pv[c];

    // S^T = K.Q^T (consumes pk)
    f32x4 st[4][4];
#pragma unroll
    for (int qb = 0; qb < 4; ++qb)
#pragma unroll
      for (int ni = 0; ni < 4; ++ni)
        st[qb][ni] = (f32x4){0.f, 0.f, 0.f, 0.f};
#pragma unroll
    for (int ks = 0; ks < 2; ++ks)
#pragma unroll
      for (int ni = 0; ni < 4; ++ni)
#pragma unroll
        for (int qb = 0; qb < 4; ++qb)
          st[qb][ni] = __builtin_amdgcn_mfma_f32_16x16x32_bf16(
              pk[ni][ks], aq[qb][ks], st[qb][ni], 0, 0, 0);

    // prefetch tile i+1 (pk/pv WAR-safe: consumed above; latency overlaps
    // the exp2 + PV phase below)
    if (it + 1 < cnt) {
      const int kb2 = kbase + 64;
#pragma unroll
      for (int ni = 0; ni < 4; ++ni)
#pragma unroll
        for (int ks = 0; ks < 2; ++ks)
          pk[ni][ks] = *(const bf16x8*)&Kp[(size_t)(kb2 + ni * 16 + nlo) * 64 +
                                           ks * 32 + g * 8];
#pragma unroll
      for (int c = 0; c < 8; ++c)
        pv[c] = *(const bf16x8*)&Vp[(size_t)(c * 8 + srow) * 2048 + kb2 + soff];
    }

    // p = exp2(st) with causal mask on the diagonal tile; l in-lane
    const bool dg = (i == n - 1);
    bf16x4 p[4][4];
#pragma unroll
    for (int qb = 0; qb < 4; ++qb) {
      const int qg = q0 + qb * 16 + nlo;
#pragma unroll
      for (int ni = 0; ni < 4; ++ni) {
        const int kg0 = kbase + ni * 16 + g * 4;
#pragma unroll
        for (int r = 0; r < 4; ++r) {
          float e = __builtin_amdgcn_exp2f(st[qb][ni][r]);
          e = (!dg || (kg0 + r <= qg)) ? e : 0.0f;
          lsum[qb] += e;
          p[qb][ni][r] = (bf16)e;
        }
      }
    }

    // O^T += V^T.P  (av read once, shared across all 4 q-subtiles)
#pragma unroll
    for (int ni = 0; ni < 4; ++ni)
#pragma unroll
      for (int mi = 0; mi < 4; ++mi) {
        bf16x4 av = *(const bf16x4*)&Vw[(mi * 16 + nlo) * 72 + ni * 16 + g * 4];
#pragma unroll
        for (int qb = 0; qb < 4; ++qb)
          oacc[qb][mi] = mfma16(av, p[qb][ni], oacc[qb][mi]);
      }
  }

  // finish l: reduce over the 4 g-groups (columns are per-nlo)
#pragma unroll
  for (int qb = 0; qb < 4; ++qb) {
    lsum[qb] += __shfl_xor(lsum[qb], 16, 64);
    lsum[qb] += __shfl_xor(lsum[qb], 32, 64);
  }

  // combine: wave1 -> LDS (column-major f32 = conflict-free), wave0 adds
  if (w == 1) {
#pragma unroll
    for (int qb = 0; qb < 4; ++qb) {
#pragma unroll
      for (int mi = 0; mi < 4; ++mi)
#pragma unroll
        for (int r = 0; r < 4; ++r)
          scratch[(qb * 16 + mi * 4 + r) * 64 + lane] = oacc[qb][mi][r];
      scratch[(64 + qb) * 64 + lane] = lsum[qb];
    }
  }
  __syncthreads();
  if (w == 0) {
    const int b = bh >> 4, hd = bh & 15;
#pragma unroll
    for (int qb = 0; qb < 4; ++qb) {
      const float l = lsum[qb] + scratch[(64 + qb) * 64 + lane];
      const float inv = 1.0f / l;
      const int q = q0 + qb * 16 + nlo;
#pragma unroll
      for (int mi = 0; mi < 4; ++mi) {
        bf16x4 o;
#pragma unroll
        for (int r = 0; r < 4; ++r)
          o[r] = (bf16)((oacc[qb][mi][r] +
                         scratch[(qb * 16 + mi * 4 + r) * 64 + lane]) * inv);
        *(bf16x4*)&Oh[((size_t)b * 2048 + q) * 1024 + hd * 64 + mi * 16 + g * 4] = o;
      }
    }
  }
}

// ---------------------------------------------------------------------------
extern "C" void kernel_launch(void* const* d_in, const int* in_sizes, int n_in,
                              void* d_out, int out_size, void* d_ws, size_t ws_size,
                              hipStream_t stream) {
  (void)in_sizes; (void)n_in; (void)out_size; (void)ws_size;
  const float* x = (const float*)d_in[0];
  const float* Wq = (const float*)d_in[1];
  const float* Wk = (const float*)d_in[2];
  const float* Wv = (const float*)d_in[3];
  const float* Wo = (const float*)d_in[4];
  float* out = (float*)d_out;
  char* ws = (char*)d_ws;

  bf16* Xh   = (bf16*)(ws);                 // 4096x1024          8 MB
  bf16* Wqkv = (bf16*)(ws + 8388608);       // 3072x1024          6 MB
  bf16* Woh  = (bf16*)(ws + 14680064);      // 1024x1024          2 MB
  bf16* Qh   = (bf16*)(ws + 16777216);      // [32][2048][64]     8 MB
  bf16* Kh   = (bf16*)(ws + 25165824);      // [32][2048][64]     8 MB
  bf16* Vt   = (bf16*)(ws + 33554432);      // [32][64][2048]     8 MB
  bf16* Oh   = (bf16*)(ws + 41943040);      // 4096x1024          8 MB

  cast_all<<<8192, 256, 0, stream>>>(x, Wq, Wk, Wv, Wo, Xh, Wqkv, Woh);
  gemm_qkv<<<dim3(24, 32), 256, 0, stream>>>(Xh, Wqkv, Qh, Kh, Vt, 1024);
  attn<<<1024, 128, 0, stream>>>(Qh, Kh, Vt, Oh);
  gemm_bt<float, 128, 64><<<dim3(16, 32), 256, 0, stream>>>(Oh, Woh, out, 4096, 1024, 1024);
}

// Round 14
// 193.997 us; speedup vs baseline: 1.1247x; 1.1247x over previous
//
#include <hip/hip_runtime.h>
#include <stdint.h>
#include <stddef.h>

typedef __bf16 bf16;
typedef __bf16 bf16x8 __attribute__((ext_vector_type(8)));
typedef __bf16 bf16x4 __attribute__((ext_vector_type(4)));
typedef short short4v __attribute__((ext_vector_type(4)));
typedef float f32x4 __attribute__((ext_vector_type(4)));

#define GAS __attribute__((address_space(1)))
#define LAS __attribute__((address_space(3)))

__device__ __forceinline__ void async_load16(const void* g, void* l) {
  __builtin_amdgcn_global_load_lds((const GAS void*)g, (LAS void*)l, 16, 0, 0);
}

// 16x16x16 bf16 MFMA. C-layout of a 16x16 MFMA == B-layout of this shape,
// so P^T feeds PV straight from registers. Host pass gets a stub.
__device__ __forceinline__ f32x4 mfma16(bf16x4 a, bf16x4 b, f32x4 c) {
#if defined(__HIP_DEVICE_COMPILE__)
#if __has_builtin(__builtin_amdgcn_mfma_f32_16x16x16bf16_1k)
  return __builtin_amdgcn_mfma_f32_16x16x16bf16_1k(
      __builtin_bit_cast(short4v, a), __builtin_bit_cast(short4v, b), c, 0, 0, 0);
#else
  f32x4 d;
  asm volatile("v_mfma_f32_16x16x16_bf16 %0, %1, %2, %3"
               : "=v"(d)
               : "v"(a), "v"(b), "v"(c));
  return d;
#endif
#else
  (void)a; (void)b;
  return c;
#endif
}

// ---------------------------------------------------------------------------
// Kernel 1: fp32 -> bf16 casts, x4 vectorized. Wq pre-scaled by 0.125*log2(e)
// so QK^T lands in the exp2 domain (scores bounded -> no max subtraction).
// ---------------------------------------------------------------------------
__global__ __launch_bounds__(256) void cast_all(
    const float* __restrict__ x, const float* __restrict__ Wq,
    const float* __restrict__ Wk, const float* __restrict__ Wv,
    const float* __restrict__ Wo, bf16* __restrict__ Xh,
    bf16* __restrict__ Wqkv, bf16* __restrict__ Woh) {
  int idx = (blockIdx.x * 256 + threadIdx.x) * 4;
  const float* src;
  bf16* dst;
  float scale = 1.0f;
  if (idx < 4194304) {
    src = x + idx; dst = Xh + idx;
  } else if (idx < 7340032) {
    int j = idx - 4194304;
    if (j < 1048576) {
      src = Wq + j; scale = 0.18033688011112042f;
    } else {
      src = ((j < 2097152) ? Wk : Wv) + (j & 1048575);
    }
    dst = Wqkv + j;
  } else {
    int j = idx - 7340032;
    src = Wo + j; dst = Woh + j;
  }
  float4 v = *(const float4*)src;
  bf16x4 o;
  o[0] = (bf16)(v.x * scale); o[1] = (bf16)(v.y * scale);
  o[2] = (bf16)(v.z * scale); o[3] = (bf16)(v.w * scale);
  *(bf16x4*)dst = o;
}

// ---------------------------------------------------------------------------
// Kernel 2: QKV projection with FUSED RoPE + V-transpose epilogue.
// C-layout puts rope pairs (col 2k, 2k+1) in adjacent lanes -> shfl_xor(1)
// exchange + in-register rotation on fp32 acc. Q -> Qh, K -> Kh (both
// [bh][s][64]), V -> Vt[bh][64][2048]. No QKV intermediate buffer.
// ---------------------------------------------------------------------------
__global__ __launch_bounds__(256) void gemm_qkv(
    const bf16* __restrict__ A, const bf16* __restrict__ B,
    bf16* __restrict__ Qh, bf16* __restrict__ Kh, bf16* __restrict__ Vt,
    int K) {
  __shared__ __align__(16) bf16 As[128 * 32];
  __shared__ __align__(16) bf16 Bs[128 * 32];
  const int tid = threadIdx.x;
  const int wave = tid >> 6, lane = tid & 63;
  const int bm = blockIdx.y * 128, bn = blockIdx.x * 128;
  const int wm = (wave >> 1) * 64, wn = (wave & 1) * 64;
  const int lrow = lane >> 2, lk = (lane & 3) * 8;
  const int fr = lane & 15, fk = (lane >> 4) * 8;

  f32x4 acc[4][4] = {};

  for (int kt = 0; kt < K; kt += 32) {
    __syncthreads();
#pragma unroll
    for (int c = 0; c < 2; ++c) {
      const int chunk = wave * 2 + c;
      const bf16* ga = A + (size_t)(bm + chunk * 16 + lrow) * K + kt + lk;
      async_load16(ga, (void*)(As + chunk * 512));
      const bf16* gb = B + (size_t)(bn + chunk * 16 + lrow) * K + kt + lk;
      async_load16(gb, (void*)(Bs + chunk * 512));
    }
    __syncthreads();

    bf16x8 af[4], bfr[4];
#pragma unroll
    for (int i = 0; i < 4; ++i)
      af[i] = *(const bf16x8*)&As[(wm + i * 16 + fr) * 32 + fk];
#pragma unroll
    for (int j = 0; j < 4; ++j)
      bfr[j] = *(const bf16x8*)&Bs[(wn + j * 16 + fr) * 32 + fk];
#pragma unroll
    for (int i = 0; i < 4; ++i)
#pragma unroll
      for (int j = 0; j < 4; ++j)
        acc[i][j] =
            __builtin_amdgcn_mfma_f32_16x16x32_bf16(af[i], bfr[j], acc[i][j], 0, 0, 0);
  }

  const int r0 = (lane >> 4) * 4, cc = lane & 15;
  const bool oddl = cc & 1;
#pragma unroll
  for (int i = 0; i < 4; ++i) {
    const int row0 = bm + wm + i * 16 + r0;
    const int b = row0 >> 11, s0 = row0 & 2047;
#pragma unroll
    for (int j = 0; j < 4; ++j) {
      const int col = bn + wn + j * 16 + cc;  // whole wave same region per j
      if (col < 2048) {
        // RoPE: pair partner is lane^1 (col 2k <-> 2k+1)
        const int hcol = col & 1023;
        const int h = hcol >> 6, d = hcol & 63;
        const int ip = d >> 1;
        const float freq = __expf((float)ip * -0.2878231366242557f);
        bf16* dst = (col < 1024 ? Qh : Kh) + ((size_t)(b * 16 + h) * 2048) * 64 + d;
#pragma unroll
        for (int r = 0; r < 4; ++r) {
          float own = acc[i][j][r];
          float oth = __shfl_xor(own, 1, 64);
          float sn, cs;
          __sincosf((float)(s0 + r) * freq, &sn, &cs);
          float res = oddl ? (oth * sn + own * cs) : (own * cs - oth * sn);
          dst[(size_t)(s0 + r) * 64] = (bf16)res;
        }
      } else {
        const int v = col - 2048, h = v >> 6, d = v & 63;
        bf16x4 o;
#pragma unroll
        for (int r = 0; r < 4; ++r) o[r] = (bf16)acc[i][j][r];
        *(bf16x4*)&Vt[(((size_t)b * 16 + h) * 64 + d) * 2048 + s0] = o;
      }
    }
  }
}

// ---------------------------------------------------------------------------
// Kernel 2b (out-proj): C(MxN) = A(MxK) @ B(NxK)^T, fp32 out.
// Round 14: 128x128 tile (256 blocks = exact 1/CU; 2x MFMA per staging chunk
// vs 128x64 — m103 tile-space says 128-square is the sweet spot).
// ---------------------------------------------------------------------------
template <typename OutT, int BM, int BN>
__global__ __launch_bounds__(256) void gemm_bt(
    const bf16* __restrict__ A, const bf16* __restrict__ B,
    OutT* __restrict__ C, int M, int N, int K) {
  constexpr int ACH = BM / 16, NCH = (BM + BN) / 16, PW = NCH / 4;
  constexpr int FM = BM / 32, FN = BN / 32;
  __shared__ __align__(16) bf16 As[BM * 32];
  __shared__ __align__(16) bf16 Bs[BN * 32];
  const int tid = threadIdx.x;
  const int wave = tid >> 6, lane = tid & 63;
  const int bm = blockIdx.y * BM, bn = blockIdx.x * BN;
  const int wm = (wave >> 1) * (BM / 2), wn = (wave & 1) * (BN / 2);
  const int lrow = lane >> 2, lk = (lane & 3) * 8;
  const int fr = lane & 15, fk = (lane >> 4) * 8;

  f32x4 acc[FM][FN] = {};

  for (int kt = 0; kt < K; kt += 32) {
    __syncthreads();
#pragma unroll
    for (int c = 0; c < PW; ++c) {
      const int chunk = wave * PW + c;
      if (chunk < ACH) {
        const bf16* ga = A + (size_t)(bm + chunk * 16 + lrow) * K + kt + lk;
        async_load16(ga, (void*)(As + chunk * 512));
      } else {
        const int bc = chunk - ACH;
        const bf16* gb = B + (size_t)(bn + bc * 16 + lrow) * K + kt + lk;
        async_load16(gb, (void*)(Bs + bc * 512));
      }
    }
    __syncthreads();

    bf16x8 af[FM], bfr[FN];
#pragma unroll
    for (int i = 0; i < FM; ++i)
      af[i] = *(const bf16x8*)&As[(wm + i * 16 + fr) * 32 + fk];
#pragma unroll
    for (int j = 0; j < FN; ++j)
      bfr[j] = *(const bf16x8*)&Bs[(wn + j * 16 + fr) * 32 + fk];
#pragma unroll
    for (int i = 0; i < FM; ++i)
#pragma unroll
      for (int j = 0; j < FN; ++j)
        acc[i][j] =
            __builtin_amdgcn_mfma_f32_16x16x32_bf16(af[i], bfr[j], acc[i][j], 0, 0, 0);
  }

  const int r0 = (lane >> 4) * 4, cc = lane & 15;
#pragma unroll
  for (int i = 0; i < FM; ++i)
#pragma unroll
    for (int j = 0; j < FN; ++j)
#pragma unroll
      for (int r = 0; r < 4; ++r)
        C[(size_t)(bm + wm + i * 16 + r0 + r) * N + (bn + wn + j * 16 + cc)] =
            (OutT)acc[i][j][r];
}

// ---------------------------------------------------------------------------
// Kernel 3: causal attention — round-12 configuration VERBATIM (52.6us,
// VGPR 128, zero spill; r9/r10/r13 proved persistent-pk always spills here).
// Block = 128 threads = 2 INDEPENDENT waves splitting one 64-row Q-tile's
// key range (unnormalized exp2 streaming is additive). Barrier-free k-loop:
// private padded Vs per wave, K frags at point of use from global (L2-hot),
// V register-prefetch 1 tile ahead, P in regs (C-layout == 16x16x16
// B-layout), l in-lane + 2 end shuffles. One barrier total for combine.
// ---------------------------------------------------------------------------
__global__ __launch_bounds__(128, 2) void attn(const bf16* __restrict__ Qh,
                                               const bf16* __restrict__ Kh,
                                               const bf16* __restrict__ Vt,
                                               bf16* __restrict__ Oh) {
  __shared__ __align__(16) bf16 Vs[2][64 * 72];  // per-wave private
  __shared__ float scratch[68 * 64];             // combine area
  const int f = blockIdx.x;
  const int qt = 31 - (f >> 5);  // LPT: longest (qt=31) blocks dispatch first
  const int bh = f & 31;
  const int tid = threadIdx.x, w = tid >> 6, lane = tid & 63;
  const int nlo = lane & 15, g = lane >> 4;
  const int q0 = qt * 64;
  const bf16* __restrict__ Qp = Qh + (size_t)bh * 131072;
  const bf16* __restrict__ Kp = Kh + (size_t)bh * 131072;
  const bf16* __restrict__ Vp = Vt + (size_t)bh * 131072;
  const int n = qt + 1;          // total k-tiles for this Q-tile
  const int hf = (n + 1) >> 1;   // wave0: [0,hf), wave1: [hf,n)
  const int t0 = w ? hf : 0;
  const int cnt = w ? (n - hf) : hf;

  // Q fragments, all 4 q-subtiles (B-operand: n=q=nlo, k=d=g*8+j)
  bf16x8 aq[4][2];
#pragma unroll
  for (int qb = 0; qb < 4; ++qb)
#pragma unroll
    for (int ks = 0; ks < 2; ++ks)
      aq[qb][ks] =
          *(const bf16x8*)&Qp[(size_t)(q0 + qb * 16 + nlo) * 64 + ks * 32 + g * 8];

  f32x4 oacc[4][4] = {};  // [qb][d-block], O^T C-layout (m=d, n=q)
  float lsum[4] = {0.f, 0.f, 0.f, 0.f};

  // V staging geometry: instr c covers rows c*8..c*8+7
  const int srow = lane >> 3, soff = (lane & 7) * 8;
  bf16* __restrict__ Vw = Vs[w];

  bf16x8 pv[8];
  if (cnt > 0) {
#pragma unroll
    for (int c = 0; c < 8; ++c)
      pv[c] = *(const bf16x8*)&Vp[(size_t)(c * 8 + srow) * 2048 + t0 * 64 + soff];
  }

  for (int it = 0; it < cnt; ++it) {
    const int i = t0 + it, kbase = i * 64;
    // K fragments straight from global (L2-hot; transient registers)
    bf16x8 pk[4][2];
#pragma unroll
    for (int ni = 0; ni < 4; ++ni)
#pragma unroll
      for (int ks = 0; ks < 2; ++ks)
        pk[ni][ks] = *(const bf16x8*)&Kp[(size_t)(kbase + ni * 16 + nlo) * 64 +
                                         ks * 32 + g * 8];
    // commit V tile (wave-private; waitcnt ordering only, no barrier)
#pragma unroll
    for (int c = 0; c < 8; ++c)
      *(bf16x8*)&Vw[(c * 8 + srow) * 72 + soff] = pv[c];
    // prefetch next V tile
    if (it + 1 < cnt) {
      const int kb2 = kbase + 64;
#pragma unroll
      for (int c = 0; c < 8; ++c)
        pv[c] = *(const bf16x8*)&Vp[(size_t)(c * 8 + srow) * 2048 + kb2 + soff];
    }

    // S^T = K.Q^T, p = exp2(S^T) in regs, l accumulated in-lane
    const bool dg = (i == n - 1);
    bf16x4 p[4][4];
#pragma unroll
    for (int qb = 0; qb < 4; ++qb) {
      f32x4 st[4] = {};
#pragma unroll
      for (int ks = 0; ks < 2; ++ks)
#pragma unroll
        for (int ni = 0; ni < 4; ++ni)
          st[ni] = __builtin_amdgcn_mfma_f32_16x16x32_bf16(pk[ni][ks], aq[qb][ks],
                                                           st[ni], 0, 0, 0);
      const int qg = q0 + qb * 16 + nlo;
#pragma unroll
      for (int ni = 0; ni < 4; ++ni) {
        const int kg0 = kbase + ni * 16 + g * 4;
#pragma unroll
        for (int r = 0; r < 4; ++r) {
          float e = __builtin_amdgcn_exp2f(st[ni][r]);
          e = (!dg || (kg0 + r <= qg)) ? e : 0.0f;
          lsum[qb] += e;
          p[qb][ni][r] = (bf16)e;
        }
      }
    }

    // O^T += V^T.P  (av read once, shared across all 4 q-subtiles)
#pragma unroll
    for (int ni = 0; ni < 4; ++ni)
#pragma unroll
      for (int mi = 0; mi < 4; ++mi) {
        bf16x4 av = *(const bf16x4*)&Vw[(mi * 16 + nlo) * 72 + ni * 16 + g * 4];
#pragma unroll
        for (int qb = 0; qb < 4; ++qb)
          oacc[qb][mi] = mfma16(av, p[qb][ni], oacc[qb][mi]);
      }
  }

  // finish l: reduce over the 4 g-groups (columns are per-nlo)
#pragma unroll
  for (int qb = 0; qb < 4; ++qb) {
    lsum[qb] += __shfl_xor(lsum[qb], 16, 64);
    lsum[qb] += __shfl_xor(lsum[qb], 32, 64);
  }

  // combine: wave1 -> LDS (column-major f32 = conflict-free), wave0 adds
  if (w == 1) {
#pragma unroll
    for (int qb = 0; qb < 4; ++qb) {
#pragma unroll
      for (int mi = 0; mi < 4; ++mi)
#pragma unroll
        for (int r = 0; r < 4; ++r)
          scratch[(qb * 16 + mi * 4 + r) * 64 + lane] = oacc[qb][mi][r];
      scratch[(64 + qb) * 64 + lane] = lsum[qb];
    }
  }
  __syncthreads();
  if (w == 0) {
    const int b = bh >> 4, hd = bh & 15;
#pragma unroll
    for (int qb = 0; qb < 4; ++qb) {
      const float l = lsum[qb] + scratch[(64 + qb) * 64 + lane];
      const float inv = 1.0f / l;
      const int q = q0 + qb * 16 + nlo;
#pragma unroll
      for (int mi = 0; mi < 4; ++mi) {
        bf16x4 o;
#pragma unroll
        for (int r = 0; r < 4; ++r)
          o[r] = (bf16)((oacc[qb][mi][r] +
                         scratch[(qb * 16 + mi * 4 + r) * 64 + lane]) * inv);
        *(bf16x4*)&Oh[((size_t)b * 2048 + q) * 1024 + hd * 64 + mi * 16 + g * 4] = o;
      }
    }
  }
}

// ---------------------------------------------------------------------------
extern "C" void kernel_launch(void* const* d_in, const int* in_sizes, int n_in,
                              void* d_out, int out_size, void* d_ws, size_t ws_size,
                              hipStream_t stream) {
  (void)in_sizes; (void)n_in; (void)out_size; (void)ws_size;
  const float* x = (const float*)d_in[0];
  const float* Wq = (const float*)d_in[1];
  const float* Wk = (const float*)d_in[2];
  const float* Wv = (const float*)d_in[3];
  const float* Wo = (const float*)d_in[4];
  float* out = (float*)d_out;
  char* ws = (char*)d_ws;

  bf16* Xh   = (bf16*)(ws);                 // 4096x1024          8 MB
  bf16* Wqkv = (bf16*)(ws + 8388608);       // 3072x1024          6 MB
  bf16* Woh  = (bf16*)(ws + 14680064);      // 1024x1024          2 MB
  bf16* Qh   = (bf16*)(ws + 16777216);      // [32][2048][64]     8 MB
  bf16* Kh   = (bf16*)(ws + 25165824);      // [32][2048][64]     8 MB
  bf16* Vt   = (bf16*)(ws + 33554432);      // [32][64][2048]     8 MB
  bf16* Oh   = (bf16*)(ws + 41943040);      // 4096x1024          8 MB

  cast_all<<<8192, 256, 0, stream>>>(x, Wq, Wk, Wv, Wo, Xh, Wqkv, Woh);
  gemm_qkv<<<dim3(24, 32), 256, 0, stream>>>(Xh, Wqkv, Qh, Kh, Vt, 1024);
  attn<<<1024, 128, 0, stream>>>(Qh, Kh, Vt, Oh);
  gemm_bt<float, 128, 128><<<dim3(8, 32), 256, 0, stream>>>(Oh, Woh, out, 4096, 1024, 1024);
}